// Round 5
// baseline (524.008 us; speedup 1.0000x reference)
//
#include <hip/hip_runtime.h>

#define BB 16
#define CC 16
#define HH 384
#define WW 384
#define HWSZ (HH*WW)
#define CHW (CC*HWSZ)
#define NPIX (BB*CHW)
#define KS 11

#define K2_THREADS 256
#define K2_HSEGS 12
#define K2_SEGH (HH/K2_HSEGS)    // 32 rows per segment (halo 10/32 = 31%)
#define W8 (WW/8)                // 48 uint4-groups per row
#define ROWU4 (WW/8)

typedef unsigned short ushortT;

// ---- bf16 helpers (raw-bit, RNE) -----------------------------------------
__device__ __forceinline__ float bf2f(ushortT h) {
    union { unsigned u; float f; } c; c.u = ((unsigned)h) << 16; return c.f;
}
__device__ __forceinline__ ushortT f2bf(float f) {
    union { float f; unsigned u; } c; c.f = f;
    unsigned r = c.u + 0x7FFFu + ((c.u >> 16) & 1u);
    return (ushortT)(r >> 16);
}
__device__ __forceinline__ void unpk2(unsigned u, float& lo, float& hi) {
    union { unsigned u; float f; } a, b;
    a.u = u << 16; b.u = u & 0xFFFF0000u;
    lo = a.f; hi = b.f;
}
__device__ __forceinline__ unsigned pk2(float lo, float hi) {
    return ((unsigned)f2bf(hi) << 16) | (unsigned)f2bf(lo);
}
__device__ __forceinline__ void unpk8(const uint4& q, float* v) {
    unpk2(q.x, v[0], v[1]); unpk2(q.y, v[2], v[3]);
    unpk2(q.z, v[4], v[5]); unpk2(q.w, v[6], v[7]);
}
__device__ __forceinline__ uint4 pk8(const float* v) {
    uint4 q;
    q.x = pk2(v[0], v[1]); q.y = pk2(v[2], v[3]);
    q.z = pk2(v[4], v[5]); q.w = pk2(v[6], v[7]);
    return q;
}

// ---------------------------------------------------------------------------
// K1: vectorized softmax+ConvW.  Wave = one (b,h) row; lane g owns 8 cols
// (uint4 bf16) for all 16 channels.  In-thread softmax; ConvW halo via
// f32 lane shuffles (lane +-1 = cols +-8).  No LDS, no barriers.
// F32IN: iter-0 variant reads f32 x0 and additionally writes x0b (bf16).
// ---------------------------------------------------------------------------
template<bool F32IN>
__global__ __launch_bounds__(256) void k_smax_convw_v(
    const void* __restrict__ xin, ushortT* __restrict__ t,
    ushortT* __restrict__ x0b,
    const float* __restrict__ spacings, const float* __restrict__ invtheta)
{
    const int lane = threadIdx.x & 63;
    const int r    = threadIdx.x >> 6;          // 4 rows per block
    const int h    = blockIdx.x * 4 + r;
    const int b    = blockIdx.y;
    const bool act = lane < 48;
    const int g    = act ? lane : 0;            // clamped for safe addresses

    const float sc = spacings[b * 2 + 1] * invtheta[1];  // W axis = spatial axis 1
    float kw[KS];
#pragma unroll
    for (int j = 0; j < KS; ++j) { float d = sc * (float)(j - 5); kw[j] = __expf(-0.5f * d * d); }
    kw[5] = 0.f;

    const size_t base = (size_t)b * CHW + (size_t)h * WW + (size_t)g * 8;

    // ---- load x (all channels) as packed bf16 ----
    uint4 xq[CC];
    if (F32IN) {
        const float* xf = (const float*)xin;
#pragma unroll
        for (int c = 0; c < CC; ++c) {
            const float4 A = *(const float4*)(xf + base + (size_t)c * HWSZ);
            const float4 B = *(const float4*)(xf + base + (size_t)c * HWSZ + 4);
            uint4 q;
            q.x = pk2(A.x, A.y); q.y = pk2(A.z, A.w);
            q.z = pk2(B.x, B.y); q.w = pk2(B.z, B.w);
            xq[c] = q;
            if (act) *(uint4*)(x0b + base + (size_t)c * HWSZ) = q;
        }
    } else {
        const ushortT* xb = (const ushortT*)xin;
#pragma unroll
        for (int c = 0; c < CC; ++c)
            xq[c] = *(const uint4*)(xb + base + (size_t)c * HWSZ);
    }

    // ---- pass 1: per-column max over channels ----
    float m[8];
    unpk8(xq[0], m);
#pragma unroll
    for (int c = 1; c < CC; ++c) {
        float v[8]; unpk8(xq[c], v);
#pragma unroll
        for (int k = 0; k < 8; ++k) m[k] = fmaxf(m[k], v[k]);
    }

    // ---- pass 2: e = exp(x - m) (overwrite xq, packed), accumulate s ----
    float s[8];
#pragma unroll
    for (int k = 0; k < 8; ++k) s[k] = 0.f;
#pragma unroll
    for (int c = 0; c < CC; ++c) {
        float v[8]; unpk8(xq[c], v);
#pragma unroll
        for (int k = 0; k < 8; ++k) { v[k] = __expf(v[k] - m[k]); s[k] += v[k]; }
        xq[c] = pk8(v);
    }
    float inv[8];
#pragma unroll
    for (int k = 0; k < 8; ++k) inv[k] = 1.0f / s[k];

    // ---- pass 3: per channel: p, halo shuffle, ConvW, store t' ----
    ushortT* tb = t + base;
#pragma unroll
    for (int c = 0; c < CC; ++c) {
        float p[8]; unpk8(xq[c], p);
#pragma unroll
        for (int k = 0; k < 8; ++k) p[k] *= inv[k];

        float win[18];
        // left halo: cols 8g-5..8g-1 = left lane's p[3..7]
        win[0] = __shfl_up(p[3], 1); win[1] = __shfl_up(p[4], 1);
        win[2] = __shfl_up(p[5], 1); win[3] = __shfl_up(p[6], 1);
        win[4] = __shfl_up(p[7], 1);
        // right halo: cols 8g+8..8g+12 = right lane's p[0..4]
        win[13] = __shfl_down(p[0], 1); win[14] = __shfl_down(p[1], 1);
        win[15] = __shfl_down(p[2], 1); win[16] = __shfl_down(p[3], 1);
        win[17] = __shfl_down(p[4], 1);
        if (g == 0)  { win[0] = win[1] = win[2] = win[3] = win[4] = 0.f; }
        if (g == 47) { win[13] = win[14] = win[15] = win[16] = win[17] = 0.f; }
#pragma unroll
        for (int k = 0; k < 8; ++k) win[5 + k] = p[k];

        float o[8];
#pragma unroll
        for (int k = 0; k < 8; ++k) {
            float acc = 0.f;
#pragma unroll
            for (int j = 0; j < KS; ++j) {
                if (j == 5) continue;
                acc = fmaf(kw[j], win[k + j], acc);
            }
            o[k] = acc;
        }
        if (act) *(uint4*)(tb + (size_t)c * HWSZ) = pk8(o);
    }
}

// ---------------------------------------------------------------------------
// K2: ConvH (rolling bf16x8 window) + x = x0b + sw*conv.  bf16 in/out.
// ---------------------------------------------------------------------------
__global__ __launch_bounds__(K2_THREADS) void k_convh_add(
    const ushortT* __restrict__ t, const ushortT* __restrict__ x0b,
    ushortT* __restrict__ xout,
    const float* __restrict__ spacings, const float* __restrict__ invtheta,
    const float* __restrict__ swp)
{
    const int colIdx = blockIdx.x * K2_THREADS + threadIdx.x;  // [0, CC*W8)
    const int c  = colIdx / W8;
    const int w8 = colIdx - c * W8;
    const int b  = blockIdx.z;
    const int h0 = blockIdx.y * K2_SEGH;

    const float sw = swp[0];
    const float sc = spacings[b * 2 + 0] * invtheta[0];  // H axis = spatial axis 0
    float kh[KS];
#pragma unroll
    for (int j = 0; j < KS; ++j) { float d = sc * (float)(j - 5); kh[j] = __expf(-0.5f * d * d); }
    kh[5] = 0.f;

    const size_t base = (size_t)(b * CC + c) * HWSZ + (size_t)w8 * 8;
    const uint4* tb = (const uint4*)(t    + base);
    const uint4* ub = (const uint4*)(x0b  + base);
    uint4*       ob = (uint4*)      (xout + base);

    const uint4 z4 = make_uint4(0u, 0u, 0u, 0u);
    uint4 win[KS];
#pragma unroll
    for (int j = 0; j < KS; ++j) {
        const int rr = h0 + j - 5;
        win[j] = ((unsigned)rr < HH) ? tb[(size_t)rr * ROWU4] : z4;
    }

#pragma unroll 4
    for (int h = h0; h < h0 + K2_SEGH; ++h) {
        const int nr = h + 6;
        const uint4 nt = (nr < HH) ? tb[(size_t)nr * ROWU4] : z4;   // prefetch
        const uint4 u  = ub[(size_t)h * ROWU4];

        float acc[8];
#pragma unroll
        for (int k = 0; k < 8; ++k) acc[k] = 0.f;
#pragma unroll
        for (int j = 0; j < KS; ++j) {
            if (j == 5) continue;
            float e[8]; unpk8(win[j], e);
            const float kj = kh[j];
#pragma unroll
            for (int k = 0; k < 8; ++k) acc[k] = fmaf(kj, e[k], acc[k]);
        }
        float uu[8]; unpk8(u, uu);
        float o[8];
#pragma unroll
        for (int k = 0; k < 8; ++k) o[k] = fmaf(sw, acc[k], uu[k]);
        ob[(size_t)h * ROWU4] = pk8(o);

#pragma unroll
        for (int j = 0; j < KS - 1; ++j) win[j] = win[j + 1];
        win[KS - 1] = nt;
    }
}

// ---------------------------------------------------------------------------
// K3: log_softmax over C, bf16 in -> f32 out.  4 pixels per thread.
// ---------------------------------------------------------------------------
__global__ __launch_bounds__(256) void k_final(
    const ushortT* __restrict__ xf, float* __restrict__ out)
{
    const int p4 = blockIdx.x * 256 + threadIdx.x;
    if (p4 >= (BB * HWSZ) / 4) return;
    const int b  = p4 / (HWSZ / 4);
    const int r4 = p4 - b * (HWSZ / 4);
    const size_t base = (size_t)b * CHW + (size_t)r4 * 4;

    float v[CC][4];
#pragma unroll
    for (int c = 0; c < CC; ++c) {
        const uint2 u = *(const uint2*)(xf + base + (size_t)c * HWSZ);
        unpk2(u.x, v[c][0], v[c][1]);
        unpk2(u.y, v[c][2], v[c][3]);
    }
#pragma unroll
    for (int k = 0; k < 4; ++k) {
        float m = v[0][k];
#pragma unroll
        for (int c = 1; c < CC; ++c) m = fmaxf(m, v[c][k]);
        float s = 0.f;
#pragma unroll
        for (int c = 0; c < CC; ++c) s += __expf(v[c][k] - m);
        const float l = m + __logf(s);
#pragma unroll
        for (int c = 0; c < CC; ++c) v[c][k] -= l;
    }
#pragma unroll
    for (int c = 0; c < CC; ++c) {
        float4 o = make_float4(v[c][0], v[c][1], v[c][2], v[c][3]);
        *(float4*)(out + base + (size_t)c * HWSZ) = o;
    }
}

// ---------------------------------------------------------------------------
extern "C" void kernel_launch(void* const* d_in, const int* in_sizes, int n_in,
                              void* d_out, int out_size, void* d_ws, size_t ws_size,
                              hipStream_t stream)
{
    const float* x0   = (const float*)d_in[0];  // (B,C,H,W) unaries f32
    const float* spac = (const float*)d_in[1];  // (B,2)
    const float* sw   = (const float*)d_in[2];  // scalar
    const float* it   = (const float*)d_in[3];  // (2,)

    ushortT* x0b = (ushortT*)d_ws;        // bf16 copy of x0 (75.5 MB)
    ushortT* t   = x0b + (size_t)NPIX;    // bf16 smoothed probs (75.5 MB)
    ushortT* xb  = (ushortT*)d_out;       // bf16 evolving x (first half of d_out)
    float*   out = (float*)d_out;         // final f32 output

    dim3 g1(HH / 4, BB);                  // (96,16), 256 threads = 4 rows
    dim3 g2(CC * W8 / K2_THREADS, K2_HSEGS, BB);   // (3, 12, 16)

    // iter 0: softmax+ConvW reading f32 x0 directly; also emits x0b (bf16)
    k_smax_convw_v<true><<<g1, dim3(256), 0, stream>>>(x0, t, x0b, spac, it);
    k_convh_add<<<g2, dim3(K2_THREADS), 0, stream>>>(t, x0b, xb, spac, it, sw);

    for (int n = 1; n < 5; ++n) {
        k_smax_convw_v<false><<<g1, dim3(256), 0, stream>>>(xb, t, x0b, spac, it);
        // last iteration writes x5 over x0b (element-wise same-thread RAW — safe);
        // x0b is regenerated every launch by iter-0, so replay-deterministic.
        k_convh_add<<<g2, dim3(K2_THREADS), 0, stream>>>(
            t, x0b, (n == 4) ? x0b : xb, spac, it, sw);
    }
    const int np4 = (BB * HWSZ) / 4;
    k_final<<<(np4 + 255) / 256, 256, 0, stream>>>(x0b, out);
}